// Round 17
// baseline (96.607 us; speedup 1.0000x reference)
//
#include <hip/hip_runtime.h>
#include <hip/hip_bf16.h>

// Problem: B=8192, DIM_IN=2048, DIM_OUT=512
//   hazards = relu(x @ W_h^T + b_h);  out = cumsum(hazards,1) + x@W_base^T + b
//
// Round 17: r16's byte-minimal k_main (BM=BN=128, all-DMA staging, counted
// vmcnt, 1 barrier/phase) but WITHOUT the precast pass: A DMA'd as f32
// straight from x (per-lane global src, linear LDS dest), f32->bf16 cvt on
// read. A-read 16-way bank alias tolerated (off critical path). 4 nj-sharers
// of each A-panel co-XCD via bijective swizzle -> x re-reads are L2 hits.

typedef __attribute__((ext_vector_type(8))) short  short8;
typedef __attribute__((ext_vector_type(4))) float  float4v;
typedef __attribute__((ext_vector_type(4))) float  f32x4;

#define DIN  2048
#define DOUT 512
#define NROW 8192
#define BM   128
#define BN   128
#define NPH  (DIN / 64)   // 32 K-phases of 64

static __device__ __forceinline__ unsigned short f2bf(float f) {
  union { float f; unsigned int u; } v; v.f = f;
  unsigned int u = v.u;
  unsigned int r = (u + 0x7FFFu + ((u >> 16) & 1u)) >> 16;   // RNE
  return (unsigned short)r;
}

static __device__ __forceinline__ void dma16(const void* g, void* l) {
  __builtin_amdgcn_global_load_lds(
      (const __attribute__((address_space(1))) unsigned int*)g,
      (__attribute__((address_space(3))) unsigned int*)l, 16, 0, 0);
}

static __device__ __forceinline__ void barrier_nd() {
  asm volatile("s_waitcnt lgkmcnt(0)" ::: "memory");
  __builtin_amdgcn_s_barrier();
}

// ---- k_pack: W[512][2048] f32 -> fragment-packed bf16 (1KB/frag) ----------
__global__ __launch_bounds__(256) void k_pack(const float* __restrict__ W,
                                              unsigned short* __restrict__ Wp) {
  int t    = blockIdx.x * 256 + threadIdx.x;   // 0..131071
  int lane = t & 63;
  int frag = t >> 6;
  int nt   = frag >> 6, ktp = frag & 63;
  int n = nt * 16 + (lane & 15);
  int k = ktp * 32 + (lane >> 4) * 8;
  const float* src = W + (size_t)n * DIN + k;
  float4v a = __builtin_nontemporal_load((const float4v*)src);
  float4v b = __builtin_nontemporal_load((const float4v*)(src + 4));
  unsigned short o[8] = { f2bf(a.x), f2bf(a.y), f2bf(a.z), f2bf(a.w),
                          f2bf(b.x), f2bf(b.y), f2bf(b.z), f2bf(b.w) };
  *(short8*)(Wp + (size_t)t * 8) = *(const short8*)o;
}

// ---- k_main: fused GEMM + bias + relu + partial row-scan + base -----------
// grid 256: bijective XCD swizzle -> bi (0..63), nj (0..3); the 4 nj-sharers
// of one A-panel are swz-consecutive -> same XCD chunk (L2 x-reuse).
// 1024 thr = 16 waves (4 wr x 4 wc), wave tile 32x32.
// Staging: per phase 48 DMAs (32 A-f32 sites + 16 B-frag sites) = 3/wave,
// triple-buffered, vmcnt(3), one barrier per phase.
__global__ __launch_bounds__(1024) void k_main(
    const float* __restrict__ x, const unsigned short* __restrict__ Wp,
    const float* __restrict__ b_h, const float* __restrict__ w_base,
    const float* __restrict__ b_base, float* __restrict__ out,
    float* __restrict__ rowTotalG, float* __restrict__ baseG) {
  __shared__ float          Afs[3 * BM * 64];   // 96 KB (3 x 32 KB, f32 [row][64])
  __shared__ unsigned short Bfs[3 * 16 * 512];  // 48 KB (3 x 16 frags x 1KB)
  __shared__ float WbL[DIN];                    // 8 KB
  __shared__ float stripT[BM][4];
  __shared__ float baseL[BM];

  const int tid  = threadIdx.x;
  const int lane = tid & 63;
  const int w    = tid >> 6;       // wave 0..15
  const int wr   = w >> 2;         // 0..3 (32-row group)
  const int wc   = w & 3;          // 0..3 (32-col strip)
  const int q    = lane >> 4;      // 0..3
  const int lm   = lane & 15;

  const int id  = blockIdx.x;
  const int swz = ((id & 7) << 5) | (id >> 3);
  const int bi  = swz >> 2;        // 0..63
  const int nj  = swz & 3;         // 0..3
  const int m0  = bi * BM;
  const bool isL = (nj == 0);

  if (isL) {  // plain loads; compiler drains them before first DMA issue
    for (int i = tid; i < DIN; i += 1024) WbL[i] = w_base[i];
  }

  f32x4 acc[2][2];
  const f32x4 z4 = {0.f, 0.f, 0.f, 0.f};
#pragma unroll
  for (int mi = 0; mi < 2; ++mi)
#pragma unroll
    for (int ni = 0; ni < 2; ++ni) acc[mi][ni] = z4;

  const char* xB  = (const char*)x + (size_t)m0 * (DIN * 4);
  const char* WpB = (const char*)Wp;
  float basePart = 0.f;

  // 3 DMAs per wave per phase: A sites {w, 16+w} (4 rows x 256B each), B site w
  auto issue = [&](int p, int b) {
#pragma unroll
    for (int s2 = 0; s2 < 2; ++s2) {
      const int s   = s2 * 16 + w;                 // A site 0..31
      const int row = s * 4 + (lane >> 4);         // per-lane row
      dma16(xB + (size_t)row * (DIN * 4) + p * 256 + (lane & 15) * 16,
            &Afs[b * 8192 + s * 256]);
    }
    const int fg = (nj * 8 + (w >> 1)) * 64 + p * 2 + (w & 1);
    dma16(WpB + (size_t)fg * 1024 + lane * 16,
          &Bfs[b * 8192 + w * 512]);
  };

  auto compute = [&](int p, int b) {
    const float*          Af = &Afs[b * 8192];
    const unsigned short* Bf = &Bfs[b * 8192];
    short8 xf[2][2], bfr[2][2];
#pragma unroll
    for (int h = 0; h < 2; ++h)
#pragma unroll
      for (int mi = 0; mi < 2; ++mi) {
        const int row = wr * 32 + mi * 16 + lm;
        const int k0  = (q + 4 * h) * 8;
        float4v fa = *(const float4v*)&Af[row * 64 + k0];
        float4v fb = *(const float4v*)&Af[row * 64 + k0 + 4];
        unsigned short t[8] = { f2bf(fa.x), f2bf(fa.y), f2bf(fa.z), f2bf(fa.w),
                                f2bf(fb.x), f2bf(fb.y), f2bf(fb.z), f2bf(fb.w) };
        xf[h][mi] = *(const short8*)t;
      }
#pragma unroll
    for (int ni = 0; ni < 2; ++ni)
#pragma unroll
      for (int h = 0; h < 2; ++h)
        bfr[ni][h] = *(const short8*)&Bf[((wc * 2 + ni) * 2 + h) * 512 + lane * 8];
#pragma unroll
    for (int h = 0; h < 2; ++h)
#pragma unroll
      for (int mi = 0; mi < 2; ++mi)
#pragma unroll
        for (int ni = 0; ni < 2; ++ni)
          acc[mi][ni] = __builtin_amdgcn_mfma_f32_16x16x32_bf16(
              bfr[ni][h], xf[h][mi], acc[mi][ni], 0, 0, 0);
    if (isL) {  // base GEMV in f32: 8 thr/row, 8 f32 each
      const int row = tid >> 3, seg = tid & 7;
      float4v fa = *(const float4v*)&Af[row * 64 + seg * 8];
      float4v fb = *(const float4v*)&Af[row * 64 + seg * 8 + 4];
      float4v wa = *(const float4v*)&WbL[p * 64 + seg * 8];
      float4v wb = *(const float4v*)&WbL[p * 64 + seg * 8 + 4];
      basePart += fa.x * wa.x + fa.y * wa.y + fa.z * wa.z + fa.w * wa.w +
                  fb.x * wb.x + fb.y * wb.y + fb.z * wb.z + fb.w * wb.w;
    }
  };

  // prologue: phases 0,1 in flight; wait own p0 (3 of 6), then sync
  issue(0, 0);
  issue(1, 1);
  asm volatile("s_waitcnt vmcnt(3)" ::: "memory");
  barrier_nd();

  for (int p = 0; p < NPH; ++p) {
    compute(p, p % 3);
    if (p + 2 < NPH) {
      issue(p + 2, (p + 2) % 3);
      asm volatile("s_waitcnt vmcnt(3)" ::: "memory");  // own p+1 landed
    } else {
      asm volatile("s_waitcnt vmcnt(0)" ::: "memory");  // tail drain
    }
    barrier_nd();
  }

  // ---- base reduce: 8 consecutive threads share a row ----
  if (isL) {
    float s = basePart;
    s += __shfl_xor(s, 1); s += __shfl_xor(s, 2); s += __shfl_xor(s, 4);
    if ((tid & 7) == 0) baseL[tid >> 3] = s + b_base[0];
  }

  // ---- epilogue: bias + relu + scan over this wave's 32-col strip ----
  float runp[2][2][4];
  float Eq[2][2];
  float niPre[2][2];
  float Tst[2];
#pragma unroll
  for (int mi = 0; mi < 2; ++mi) {
    float run = 0.f;
#pragma unroll
    for (int ni = 0; ni < 2; ++ni) {
      float4v b4 = *(const float4v*)(b_h + nj * BN + wc * 32 + ni * 16 + q * 4);
      f32x4 v = acc[mi][ni];
      float h0 = fmaxf(v.x + b4.x, 0.f);
      float h1 = fmaxf(v.y + b4.y, 0.f);
      float h2 = fmaxf(v.z + b4.z, 0.f);
      float h3 = fmaxf(v.w + b4.w, 0.f);
      runp[mi][ni][0] = h0;
      runp[mi][ni][1] = h0 + h1;
      runp[mi][ni][2] = h0 + h1 + h2;
      runp[mi][ni][3] = h0 + h1 + h2 + h3;
      float S = runp[mi][ni][3];
      float u1 = __shfl_up(S, 16);
      float u2 = __shfl_up(S, 32);
      float u3 = __shfl_up(S, 48);
      Eq[mi][ni] = (q >= 1 ? u1 : 0.f) + (q >= 2 ? u2 : 0.f) + (q >= 3 ? u3 : 0.f);
      float G = S + __shfl_xor(S, 16);
      G += __shfl_xor(G, 32);
      niPre[mi][ni] = run;
      run += G;
    }
    Tst[mi] = run;
  }
  if (q == 0) {
#pragma unroll
    for (int mi = 0; mi < 2; ++mi) stripT[wr * 32 + mi * 16 + lm][wc] = Tst[mi];
  }
  barrier_nd();

  if (tid < BM) {
    float4v s4 = *(const float4v*)&stripT[tid][0];
    rowTotalG[(size_t)(m0 + tid) * 4 + nj] = s4.x + s4.y + s4.z + s4.w;
    if (isL) baseG[m0 + tid] = baseL[tid];
  }

#pragma unroll
  for (int mi = 0; mi < 2; ++mi) {
    const int row = wr * 32 + mi * 16 + lm;
    float c = isL ? baseL[row] : 0.f;
    float4v s4 = *(const float4v*)&stripT[row][0];
    c += (wc > 0 ? s4.x : 0.f) + (wc > 1 ? s4.y : 0.f) + (wc > 2 ? s4.z : 0.f);
#pragma unroll
    for (int ni = 0; ni < 2; ++ni) {
      float base = c + niPre[mi][ni] + Eq[mi][ni];
      float4v o = { runp[mi][ni][0] + base, runp[mi][ni][1] + base,
                    runp[mi][ni][2] + base, runp[mi][ni][3] + base };
      __builtin_nontemporal_store(
          o, (float4v*)(out + (size_t)(m0 + row) * DOUT + nj * BN + wc * 32 + ni * 16 + q * 4));
    }
  }
}

// ---- k_fix: out[row][128..511] += base[row] + sum of left quarters --------
__global__ __launch_bounds__(128) void k_fix(float* __restrict__ out,
                                             const float* __restrict__ rowTotal,
                                             const float* __restrict__ base) {
  const int row = blockIdx.x;
  const int j   = threadIdx.x;
  if (j >= 96) return;
  const int s = j >> 5;                 // 0,1,2 -> quarters 1,2,3
  const float* rt = rowTotal + (size_t)row * 4;
  float pre = base[row] + rt[0];
  if (s >= 1) pre += rt[1];
  if (s >= 2) pre += rt[2];
  float4v* p = (float4v*)(out + (size_t)row * DOUT + 128 + j * 4);
  float4v v = *p;
  v.x += pre; v.y += pre; v.z += pre; v.w += pre;
  __builtin_nontemporal_store(v, p);
}

// ---------------------------------------------------------------------------
extern "C" void kernel_launch(void* const* d_in, const int* in_sizes, int n_in,
                              void* d_out, int out_size, void* d_ws, size_t ws_size,
                              hipStream_t stream) {
  const float* x   = (const float*)d_in[0];  // [8192,2048]
  const float* Wh  = (const float*)d_in[1];  // [512,2048]
  const float* bh  = (const float*)d_in[2];  // [512]
  const float* Wb0 = (const float*)d_in[3];  // [1,2048]
  const float* bb  = (const float*)d_in[4];  // [1]
  float* out = (float*)d_out;

  char* ws = (char*)d_ws;
  const size_t MB = 1024u * 1024u;
  unsigned short* Wp = (unsigned short*)ws;                    // 2 MiB
  float* rowTotal    = (float*)(ws + 2 * MB);                  // 128 KiB
  float* baseG       = (float*)(ws + 2 * MB + 256u * 1024u);   // 32 KiB

  k_pack<<<dim3((DOUT * DIN) / (256 * 8)), dim3(256), 0, stream>>>(Wh, Wp);
  k_main<<<dim3((NROW / BM) * (DOUT / BN)), dim3(1024), 0, stream>>>(
      x, Wp, bh, Wb0, bb, out, rowTotal, baseG);
  k_fix<<<dim3(NROW), dim3(128), 0, stream>>>(out, rowTotal, baseG);
}

// Round 18
// 58.792 us; speedup vs baseline: 1.6432x; 1.6432x over previous
//
#include <hip/hip_runtime.h>
#include <hip/hip_bf16.h>

// Problem: B=8192, DIM_IN=2048, DIM_OUT=512
//   hazards = relu(x @ W_h^T + b_h);  out = cumsum(hazards,1) + x@W_base^T + b
//
// Round 18: r17 (byte-minimal BM=BN=128, all-DMA, counted vmcnt(3), one
// barrier/phase) + A-tile BANK-CONFLICT FIX: DMA source granule swizzled by
// row ((lane&15)^(row&7)), LDS dest linear (DMA constraint), matching XOR on
// every A read -> b128 reads at LDS minimum. Hot-path f32->bf16 via
// v_cvt_pk (float22bfloat162_rn) instead of manual RNE.

typedef __attribute__((ext_vector_type(8))) short        short8;
typedef __attribute__((ext_vector_type(4))) float        float4v;
typedef __attribute__((ext_vector_type(4))) float        f32x4;
typedef __attribute__((ext_vector_type(4))) unsigned int uint4v;

#define DIN  2048
#define DOUT 512
#define NROW 8192
#define BM   128
#define BN   128
#define NPH  (DIN / 64)   // 32 K-phases of 64

static __device__ __forceinline__ unsigned short f2bf(float f) {
  union { float f; unsigned int u; } v; v.f = f;
  unsigned int u = v.u;
  unsigned int r = (u + 0x7FFFu + ((u >> 16) & 1u)) >> 16;   // RNE
  return (unsigned short)r;
}

static __device__ __forceinline__ unsigned int pk2(float a, float b) {
  __hip_bfloat162 h = __float22bfloat162_rn(float2{a, b});   // v_cvt_pk_bf16_f32
  union { __hip_bfloat162 h; unsigned int u; } c; c.h = h;
  return c.u;
}

static __device__ __forceinline__ void dma16(const void* g, void* l) {
  __builtin_amdgcn_global_load_lds(
      (const __attribute__((address_space(1))) unsigned int*)g,
      (__attribute__((address_space(3))) unsigned int*)l, 16, 0, 0);
}

static __device__ __forceinline__ void barrier_nd() {
  asm volatile("s_waitcnt lgkmcnt(0)" ::: "memory");
  __builtin_amdgcn_s_barrier();
}

// ---- k_pack: W[512][2048] f32 -> fragment-packed bf16 (1KB/frag) ----------
__global__ __launch_bounds__(256) void k_pack(const float* __restrict__ W,
                                              unsigned short* __restrict__ Wp) {
  int t    = blockIdx.x * 256 + threadIdx.x;   // 0..131071
  int lane = t & 63;
  int frag = t >> 6;
  int nt   = frag >> 6, ktp = frag & 63;
  int n = nt * 16 + (lane & 15);
  int k = ktp * 32 + (lane >> 4) * 8;
  const float* src = W + (size_t)n * DIN + k;
  float4v a = __builtin_nontemporal_load((const float4v*)src);
  float4v b = __builtin_nontemporal_load((const float4v*)(src + 4));
  unsigned short o[8] = { f2bf(a.x), f2bf(a.y), f2bf(a.z), f2bf(a.w),
                          f2bf(b.x), f2bf(b.y), f2bf(b.z), f2bf(b.w) };
  *(short8*)(Wp + (size_t)t * 8) = *(const short8*)o;
}

// ---- k_main: fused GEMM + bias + relu + partial row-scan + base -----------
// grid 256: bijective XCD swizzle -> bi (0..63), nj (0..3); 4 nj-sharers of
// one A-panel co-XCD (x re-reads L2-hit, verified r17 FETCH=41MB).
// 1024 thr = 16 waves (4 wr x 4 wc), wave tile 32x32.
// A LDS image: site s (1KB) holds rows s*4..s*4+3; lane l holds row
// s*4+(l>>4), granule (l&15)^(row&7)  [source-swizzled] ->
// f32 idx of (row,granule g) = row*64 + ((g^(row&7))<<2).
__global__ __launch_bounds__(1024) void k_main(
    const float* __restrict__ x, const unsigned short* __restrict__ Wp,
    const float* __restrict__ b_h, const float* __restrict__ w_base,
    const float* __restrict__ b_base, float* __restrict__ out,
    float* __restrict__ rowTotalG, float* __restrict__ baseG) {
  __shared__ float          Afs[3 * BM * 64];   // 96 KB (3 x 32 KB f32)
  __shared__ unsigned short Bfs[3 * 16 * 512];  // 48 KB
  __shared__ float WbL[DIN];                    // 8 KB
  __shared__ float stripT[BM][4];
  __shared__ float baseL[BM];

  const int tid  = threadIdx.x;
  const int lane = tid & 63;
  const int w    = tid >> 6;       // wave 0..15
  const int wr   = w >> 2;         // 0..3 (32-row group)
  const int wc   = w & 3;          // 0..3 (32-col strip)
  const int q    = lane >> 4;      // 0..3
  const int lm   = lane & 15;

  const int id  = blockIdx.x;
  const int swz = ((id & 7) << 5) | (id >> 3);
  const int bi  = swz >> 2;        // 0..63
  const int nj  = swz & 3;         // 0..3
  const int m0  = bi * BM;
  const bool isL = (nj == 0);

  if (isL) {  // plain loads; compiler drains before first DMA issue
    for (int i = tid; i < DIN; i += 1024) WbL[i] = w_base[i];
  }

  f32x4 acc[2][2];
  const f32x4 z4 = {0.f, 0.f, 0.f, 0.f};
#pragma unroll
  for (int mi = 0; mi < 2; ++mi)
#pragma unroll
    for (int ni = 0; ni < 2; ++ni) acc[mi][ni] = z4;

  const char* xB  = (const char*)x + (size_t)m0 * (DIN * 4);
  const char* WpB = (const char*)Wp;
  float basePart = 0.f;

  // 3 DMAs per wave per phase: A sites {w, 16+w}, B site w.
  // A source granule swizzled by row: (lane&15) ^ (row&7).
  auto issue = [&](int p, int b) {
#pragma unroll
    for (int s2 = 0; s2 < 2; ++s2) {
      const int s   = s2 * 16 + w;                 // A site 0..31
      const int row = s * 4 + (lane >> 4);         // per-lane row
      const int gs  = (lane & 15) ^ (row & 7);     // source granule
      dma16(xB + (size_t)row * (DIN * 4) + p * 256 + gs * 16,
            &Afs[b * 8192 + s * 256]);
    }
    const int fg = (nj * 8 + (w >> 1)) * 64 + p * 2 + (w & 1);
    dma16(WpB + (size_t)fg * 1024 + lane * 16,
          &Bfs[b * 8192 + w * 512]);
  };

  auto compute = [&](int p, int b) {
    const float*          Af = &Afs[b * 8192];
    const unsigned short* Bf = &Bfs[b * 8192];
    short8 xf[2][2], bfr[2][2];
#pragma unroll
    for (int h = 0; h < 2; ++h)
#pragma unroll
      for (int mi = 0; mi < 2; ++mi) {
        const int row = wr * 32 + mi * 16 + lm;
        const int g0  = (q + 4 * h) * 2;           // first 16B granule
        float4v fa = *(const float4v*)&Af[row * 64 + ((g0 ^ (row & 7)) << 2)];
        float4v fb = *(const float4v*)&Af[row * 64 + (((g0 + 1) ^ (row & 7)) << 2)];
        unsigned int u[4] = { pk2(fa.x, fa.y), pk2(fa.z, fa.w),
                              pk2(fb.x, fb.y), pk2(fb.z, fb.w) };
        xf[h][mi] = __builtin_bit_cast(short8, *(const uint4v*)u);
      }
#pragma unroll
    for (int ni = 0; ni < 2; ++ni)
#pragma unroll
      for (int h = 0; h < 2; ++h)
        bfr[ni][h] = *(const short8*)&Bf[((wc * 2 + ni) * 2 + h) * 512 + lane * 8];
#pragma unroll
    for (int h = 0; h < 2; ++h)
#pragma unroll
      for (int mi = 0; mi < 2; ++mi)
#pragma unroll
        for (int ni = 0; ni < 2; ++ni)
          acc[mi][ni] = __builtin_amdgcn_mfma_f32_16x16x32_bf16(
              bfr[ni][h], xf[h][mi], acc[mi][ni], 0, 0, 0);
    if (isL) {  // base GEMV in f32: 8 thr/row, granules 2seg, 2seg+1
      const int row = tid >> 3, seg = tid & 7;
      float4v fa = *(const float4v*)&Af[row * 64 + (((2 * seg)     ^ (row & 7)) << 2)];
      float4v fb = *(const float4v*)&Af[row * 64 + (((2 * seg + 1) ^ (row & 7)) << 2)];
      float4v wa = *(const float4v*)&WbL[p * 64 + seg * 8];
      float4v wb = *(const float4v*)&WbL[p * 64 + seg * 8 + 4];
      basePart += fa.x * wa.x + fa.y * wa.y + fa.z * wa.z + fa.w * wa.w +
                  fb.x * wb.x + fb.y * wb.y + fb.z * wb.z + fb.w * wb.w;
    }
  };

  // prologue: phases 0,1 in flight; wait own p0 (3 of 6), then sync
  issue(0, 0);
  issue(1, 1);
  asm volatile("s_waitcnt vmcnt(3)" ::: "memory");
  barrier_nd();

  for (int p = 0; p < NPH; ++p) {
    compute(p, p % 3);
    if (p + 2 < NPH) {
      issue(p + 2, (p + 2) % 3);
      asm volatile("s_waitcnt vmcnt(3)" ::: "memory");  // own p+1 landed
    } else {
      asm volatile("s_waitcnt vmcnt(0)" ::: "memory");  // tail drain
    }
    barrier_nd();
  }

  // ---- base reduce: 8 consecutive threads share a row ----
  if (isL) {
    float s = basePart;
    s += __shfl_xor(s, 1); s += __shfl_xor(s, 2); s += __shfl_xor(s, 4);
    if ((tid & 7) == 0) baseL[tid >> 3] = s + b_base[0];
  }

  // ---- epilogue: bias + relu + scan over this wave's 32-col strip ----
  float runp[2][2][4];
  float Eq[2][2];
  float niPre[2][2];
  float Tst[2];
#pragma unroll
  for (int mi = 0; mi < 2; ++mi) {
    float run = 0.f;
#pragma unroll
    for (int ni = 0; ni < 2; ++ni) {
      float4v b4 = *(const float4v*)(b_h + nj * BN + wc * 32 + ni * 16 + q * 4);
      f32x4 v = acc[mi][ni];
      float h0 = fmaxf(v.x + b4.x, 0.f);
      float h1 = fmaxf(v.y + b4.y, 0.f);
      float h2 = fmaxf(v.z + b4.z, 0.f);
      float h3 = fmaxf(v.w + b4.w, 0.f);
      runp[mi][ni][0] = h0;
      runp[mi][ni][1] = h0 + h1;
      runp[mi][ni][2] = h0 + h1 + h2;
      runp[mi][ni][3] = h0 + h1 + h2 + h3;
      float S = runp[mi][ni][3];
      float u1 = __shfl_up(S, 16);
      float u2 = __shfl_up(S, 32);
      float u3 = __shfl_up(S, 48);
      Eq[mi][ni] = (q >= 1 ? u1 : 0.f) + (q >= 2 ? u2 : 0.f) + (q >= 3 ? u3 : 0.f);
      float G = S + __shfl_xor(S, 16);
      G += __shfl_xor(G, 32);
      niPre[mi][ni] = run;
      run += G;
    }
    Tst[mi] = run;
  }
  if (q == 0) {
#pragma unroll
    for (int mi = 0; mi < 2; ++mi) stripT[wr * 32 + mi * 16 + lm][wc] = Tst[mi];
  }
  barrier_nd();

  if (tid < BM) {
    float4v s4 = *(const float4v*)&stripT[tid][0];
    rowTotalG[(size_t)(m0 + tid) * 4 + nj] = s4.x + s4.y + s4.z + s4.w;
    if (isL) baseG[m0 + tid] = baseL[tid];
  }

#pragma unroll
  for (int mi = 0; mi < 2; ++mi) {
    const int row = wr * 32 + mi * 16 + lm;
    float c = isL ? baseL[row] : 0.f;
    float4v s4 = *(const float4v*)&stripT[row][0];
    c += (wc > 0 ? s4.x : 0.f) + (wc > 1 ? s4.y : 0.f) + (wc > 2 ? s4.z : 0.f);
#pragma unroll
    for (int ni = 0; ni < 2; ++ni) {
      float base = c + niPre[mi][ni] + Eq[mi][ni];
      float4v o = { runp[mi][ni][0] + base, runp[mi][ni][1] + base,
                    runp[mi][ni][2] + base, runp[mi][ni][3] + base };
      __builtin_nontemporal_store(
          o, (float4v*)(out + (size_t)(m0 + row) * DOUT + nj * BN + wc * 32 + ni * 16 + q * 4));
    }
  }
}

// ---- k_fix: out[row][128..511] += base[row] + sum of left quarters --------
__global__ __launch_bounds__(128) void k_fix(float* __restrict__ out,
                                             const float* __restrict__ rowTotal,
                                             const float* __restrict__ base) {
  const int row = blockIdx.x;
  const int j   = threadIdx.x;
  if (j >= 96) return;
  const int s = j >> 5;                 // 0,1,2 -> quarters 1,2,3
  const float* rt = rowTotal + (size_t)row * 4;
  float pre = base[row] + rt[0];
  if (s >= 1) pre += rt[1];
  if (s >= 2) pre += rt[2];
  float4v* p = (float4v*)(out + (size_t)row * DOUT + 128 + j * 4);
  float4v v = *p;
  v.x += pre; v.y += pre; v.z += pre; v.w += pre;
  __builtin_nontemporal_store(v, p);
}

// ---------------------------------------------------------------------------
extern "C" void kernel_launch(void* const* d_in, const int* in_sizes, int n_in,
                              void* d_out, int out_size, void* d_ws, size_t ws_size,
                              hipStream_t stream) {
  const float* x   = (const float*)d_in[0];  // [8192,2048]
  const float* Wh  = (const float*)d_in[1];  // [512,2048]
  const float* bh  = (const float*)d_in[2];  // [512]
  const float* Wb0 = (const float*)d_in[3];  // [1,2048]
  const float* bb  = (const float*)d_in[4];  // [1]
  float* out = (float*)d_out;

  char* ws = (char*)d_ws;
  const size_t MB = 1024u * 1024u;
  unsigned short* Wp = (unsigned short*)ws;                    // 2 MiB
  float* rowTotal    = (float*)(ws + 2 * MB);                  // 128 KiB
  float* baseG       = (float*)(ws + 2 * MB + 256u * 1024u);   // 32 KiB

  k_pack<<<dim3((DOUT * DIN) / (256 * 8)), dim3(256), 0, stream>>>(Wh, Wp);
  k_main<<<dim3((NROW / BM) * (DOUT / BN)), dim3(1024), 0, stream>>>(
      x, Wp, bh, Wb0, bb, out, rowTotal, baseG);
  k_fix<<<dim3(NROW), dim3(128), 0, stream>>>(out, rowTotal, baseG);
}